// Round 6
// baseline (409.666 us; speedup 1.0000x reference)
//
#include <hip/hip_runtime.h>
#include <hip/hip_cooperative_groups.h>
#include <hip/hip_bf16.h>
#include <math.h>

namespace cg = cooperative_groups;

#define NTOK 65536
#define NEXP 8
#define NBLK 256     // cooperative grid: 1 block per CU
#define TPB 512
#define TOKPB 256    // tokens per block (4 passes x 64)

typedef __bf16 bf16_t;
typedef __bf16 bf16x8 __attribute__((ext_vector_type(8)));
typedef float f32x4 __attribute__((ext_vector_type(4)));

// async global->LDS, 16B per lane. Global addr may be per-lane (gather);
// LDS dest = wave-uniform base + lane*16.
__device__ inline void async16(const void* g, void* l) {
  __builtin_amdgcn_global_load_lds(
      (const __attribute__((address_space(1))) unsigned int*)g,
      (__attribute__((address_space(3))) unsigned int*)l, 16, 0, 0);
}

// ---- LDS arena (bytes). Regions are reused phase-by-phase (barriers/syncs
// separate every reuse). Total ~100.8 KB -> 1 block/CU (cooperative: 256
// blocks on 256 CUs).
#define OFF_XS     0        // gate: 64KB x-tile (f32, swizzled); castT tile; moe ts(32KB)
#define OFF_TS     0
#define OFF_SIDX   33024    // moe: 64 ints
#define OFF_SGV    33280    // moe: 64 floats
#define OFF_PART   65536    // gate: 7*64*9 doubles (32256 B); post-sync1: gtab 8KB
#define OFF_GTAB   65536
#define OFF_BIL    98304    // 256 ints: per-token argmax expert
#define OFF_LOC    99328    // 256 ints: block-local expert-ordered (tok | e<<20)
#define OFF_CNTPE  100352   // [4][8] int per-pass counts
#define OFF_EXCLP  100480   // [4][8] int pass-exclusive prefixes
#define OFF_LB     100608   // [9] int block-local expert bases
#define OFF_SB     100648   // [8] int global scatter base for this block
#define OFF_TOTL   100680   // [8] int block-local totals
#define OFF_TOT    100712   // [8] int global expert totals
#define OFF_EB     100744   // [8] int global expert bases
#define OFF_T      100776   // int total tiles
#define ARENA_SZ   100784

// Single cooperative kernel: castT + gate + (sync) + prefix/scatter + (sync)
// + fused moe GEMM. Eliminates 5 of 6 launches (~10us gap each) and the gate
// counter atomics (1024 same-line returning atomicAdds ~= 30-40us serialized;
// replaced by a deterministic block-count table + redundant prefix sum).
// Gate numerics = validated v6 (8 segs x 32 dims, same fmaf chains, double
// partials, same softmax). moe body = validated round-5 kernel verbatim.
// idxbuf becomes DENSE (expert-major, block-major within expert); token
// order within an expert changes, which is output-invariant.
__global__ __launch_bounds__(TPB) void mega_kernel(
    const float* __restrict__ x, const float* __restrict__ wg,
    const float* __restrict__ W1, const float* __restrict__ b1,
    const float* __restrict__ W2, const float* __restrict__ b2,
    float* __restrict__ out, bf16_t* __restrict__ xb,
    bf16_t* __restrict__ w1t, bf16_t* __restrict__ w2t,
    int* __restrict__ idxbuf, float* __restrict__ gv,
    int* __restrict__ gcnt) {
  __shared__ __align__(16) char arena[ARENA_SZ];
  float*  xs    = (float*)(arena + OFF_XS);
  double* part  = (double*)(arena + OFF_PART);
  int*    bil   = (int*)(arena + OFF_BIL);
  int*    loc   = (int*)(arena + OFF_LOC);
  int*    cntpe = (int*)(arena + OFF_CNTPE);
  int*    exclp = (int*)(arena + OFF_EXCLP);
  int*    lb    = (int*)(arena + OFF_LB);
  int*    sbx   = (int*)(arena + OFF_SB);
  int*    totl  = (int*)(arena + OFF_TOTL);
  int*    tot   = (int*)(arena + OFF_TOT);
  int*    ebx   = (int*)(arena + OFF_EB);
  int*    Tsh   = (int*)(arena + OFF_T);

  const int th   = threadIdx.x;
  const int lane = th & 63;
  const int wv   = th >> 6;          // 0..7
  const int b    = blockIdx.x;
  cg::grid_group grid = cg::this_grid();

  // ================= Stage 0: weight cast+transpose (ex-castT) ============
  {
    float* tile = (float*)(arena);   // [32][33]
    for (int j = b; j < 1024; j += NBLK) {   // exactly 4 jobs per block
      const int m = j >> 6;
      const int bx = (j >> 3) & 7, by = j & 7;
      const float* src = (m < 8) ? (W1 + (size_t)m * 65536) : (W2 + (size_t)(m - 8) * 65536);
      bf16_t* dst = (m < 8) ? (w1t + (size_t)m * 65536) : (w2t + (size_t)(m - 8) * 65536);
      const int x0 = bx * 32, y0 = by * 32;
      if (th < 256) {
        int tx = th & 31, ty = th >> 5;
#pragma unroll
        for (int i = 0; i < 4; ++i)
          tile[(ty + i * 8) * 33 + tx] = src[(size_t)(y0 + ty + i * 8) * 256 + x0 + tx];
      }
      __syncthreads();
      if (th < 256) {
        int tx = th & 31, ty = th >> 5;
#pragma unroll
        for (int i = 0; i < 4; ++i)
          dst[(size_t)(x0 + ty + i * 8) * 256 + y0 + tx] = (bf16_t)tile[tx * 33 + ty + i * 8];
      }
      __syncthreads();
    }
  }

  // ================= Stage 1: gate (v6 numerics), 4 passes x 64 tokens ====
  const int xm = lane & 31;
  for (int p = 0; p < 4; ++p) {
    const int tokbase = b * TOKPB + p * 64;
    // stage 64 rows x 1KB, source pre-swizzled (slot c' holds c'^(r&31))
#pragma unroll
    for (int i = 0; i < 8; ++i) {
      int q = i * 512 + th;
      int r = q >> 6;
      int c = (q & 63) ^ (r & 31);
      async16(x + (size_t)(tokbase + r) * 256 + c * 4, &xs[(i * 512 + wv * 64) * 4]);
    }
    __syncthreads();
    // cast pass -> xb (contiguous dwordx4 stores)
#pragma unroll
    for (int i = 0; i < 4; ++i) {
      int q = i * 512 + th;
      int r = q >> 5, cb = q & 31, mk = r & 31;
      f32x4 a = *(const f32x4*)&xs[r * 256 + (((2 * cb) ^ mk) * 4)];
      f32x4 bb = *(const f32x4*)&xs[r * 256 + (((2 * cb + 1) ^ mk) * 4)];
      bf16x8 bv;
      bv[0] = (bf16_t)a[0]; bv[1] = (bf16_t)a[1];
      bv[2] = (bf16_t)a[2]; bv[3] = (bf16_t)a[3];
      bv[4] = (bf16_t)bb[0]; bv[5] = (bf16_t)bb[1];
      bv[6] = (bf16_t)bb[2]; bv[7] = (bf16_t)bb[3];
      *(bf16x8*)(xb + (size_t)tokbase * 256 + (size_t)q * 8) = bv;
    }
    // partial dots: seg wv covers dims [wv*32, wv*32+32), 4 chains of 8
    double acc[8] = {0, 0, 0, 0, 0, 0, 0, 0};
#pragma unroll
    for (int g = 0; g < 4; ++g) {
      int c0 = wv * 8 + 2 * g;
      f32x4 a = *(const f32x4*)&xs[lane * 256 + ((c0 ^ xm) * 4)];
      f32x4 bb = *(const f32x4*)&xs[lane * 256 + (((c0 + 1) ^ xm) * 4)];
      float xv[8] = {a[0], a[1], a[2], a[3], bb[0], bb[1], bb[2], bb[3]};
#pragma unroll
      for (int e = 0; e < 8; ++e) {
        const float* wge = wg + e * 256 + wv * 32 + g * 8;  // wave-uniform
        float s = 0.f;
#pragma unroll
        for (int j2 = 0; j2 < 8; ++j2) s = fmaf(xv[j2], wge[j2], s);
        acc[e] += (double)s;
      }
    }
    if (wv > 0) {
#pragma unroll
      for (int e = 0; e < 8; ++e) part[((wv - 1) * 64 + lane) * 9 + e] = acc[e];
    }
    __syncthreads();
    if (wv == 0) {
#pragma unroll
      for (int s2 = 0; s2 < 7; ++s2)
#pragma unroll
        for (int e = 0; e < 8; ++e) acc[e] += part[(s2 * 64 + lane) * 9 + e];
      double m = acc[0]; int bi = 0;
#pragma unroll
      for (int e = 1; e < 8; ++e) if (acc[e] > m) { m = acc[e]; bi = e; }
      float denom = 0.f;
#pragma unroll
      for (int e = 0; e < 8; ++e) denom += __expf((float)(acc[e] - m));
      gv[tokbase + lane] = 1.0f / denom;
      bil[p * 64 + lane] = bi;
    }
    __syncthreads();
  }

  // ---- block-local ordering (no atomics): ballot ranks + count table ----
  int myrank = 0, mybi = 0;
  if (wv < 4) {
    mybi = bil[wv * 64 + lane];
    unsigned long long below = (1ull << lane) - 1ull;
#pragma unroll
    for (int e = 0; e < 8; ++e) {
      unsigned long long mk = __ballot(mybi == e);
      if (lane == e) cntpe[wv * 8 + e] = (int)__popcll(mk);
      if (mybi == e) myrank = (int)__popcll(mk & below);
    }
  }
  __syncthreads();
  if (th < 32) {
    int w = th >> 3, e = th & 7, s = 0;
    for (int w2 = 0; w2 < w; ++w2) s += cntpe[w2 * 8 + e];
    exclp[th] = s;
  }
  if (th < 8) {
    int s = 0;
#pragma unroll
    for (int w2 = 0; w2 < 4; ++w2) s += cntpe[w2 * 8 + th];
    totl[th] = s;
    gcnt[b * 8 + th] = s;          // global per-block count table
  }
  __syncthreads();
  if (th == 0) {
    lb[0] = 0;
    for (int e = 0; e < 8; ++e) lb[e + 1] = lb[e] + totl[e];
  }
  __syncthreads();
  if (wv < 4) {
    int tk = b * TOKPB + wv * 64 + lane;
    loc[lb[mybi] + exclp[wv * 8 + mybi] + myrank] = tk | (mybi << 20);
  }
  __threadfence();
  grid.sync();   // xb, gv, gcnt globally visible

  // ================= Stage 2: prefix over blocks + scatter ================
  {
    int* gtab = (int*)(arena + OFF_GTAB);
#pragma unroll
    for (int i = 0; i < 4; ++i) gtab[i * 512 + th] = gcnt[i * 512 + th];
    __syncthreads();
    // wave e: tot[e] and sum over blocks b' < b (for this block's base)
    {
      int e = wv, s = 0, pre = 0;
#pragma unroll
      for (int k = 0; k < 4; ++k) {
        int b2 = lane * 4 + k;
        int v = gtab[b2 * 8 + e];
        s += v;
        if (b2 < b) pre += v;
      }
#pragma unroll
      for (int o = 1; o < 64; o <<= 1) {
        s += __shfl_xor(s, o, 64);
        pre += __shfl_xor(pre, o, 64);
      }
      if (lane == 0) { tot[e] = s; sbx[e] = pre; }
    }
    __syncthreads();
    if (th == 0) {
      int a2 = 0, Tt = 0;
      for (int e = 0; e < 8; ++e) {
        ebx[e] = a2; a2 += tot[e];
        Tt += (tot[e] + 63) >> 6;
        sbx[e] = ebx[e] + sbx[e];
      }
      *Tsh = Tt;
    }
    __syncthreads();
    if (th < 256) {   // scatter this block's ordered tokens to dense idxbuf
      int val = loc[th];
      int bi2 = val >> 20, tk = val & 0xFFFFF;
      idxbuf[sbx[bi2] + (th - lb[bi2])] = tk;
    }
  }
  __threadfence();
  grid.sync();   // idxbuf complete

  // ================= Stage 3: fused moe GEMM (round-5 body) ===============
  bf16_t* ts = (bf16_t*)(arena + OFF_TS);
  int* sidx = (int*)(arena + OFF_SIDX);
  float* sgv = (float*)(arena + OFF_SGV);
  const int T = *Tsh;
  const int lr = lane & 15, lq = lane >> 4;
  for (int t = b; t < T; t += NBLK) {
    int ex = 0, tm = 0, a2 = 0;
#pragma unroll
    for (int e2 = 0; e2 < 8; ++e2) {
      int ne = (tot[e2] + 63) >> 6;
      if (t >= a2 && t < a2 + ne) { ex = e2; tm = t - a2; }
      a2 += ne;
    }
    const int ccnt = tot[ex];
    const int base = ebx[ex];
    if (th < 64) {
      int r = tm * 64 + th;
      int tk = idxbuf[base + (r < ccnt ? r : ccnt - 1)];
      sidx[th] = tk;
      sgv[th] = gv[tk];
    }
    __syncthreads();
#pragma unroll
    for (int i = 0; i < 4; ++i) {
      int q = i * 512 + th;
      int r = q >> 5, s = (q & 31) ^ (r & 31);
      async16(xb + (size_t)sidx[r] * 256 + s * 8, &ts[(i * 512 + wv * 64) * 8]);
    }
    __syncthreads();
    // Phase 1: h = relu(x @ W1 + b1); wave wv owns cols wv*32..+32
    const bf16_t* w1e = w1t + (size_t)ex * 65536;
    {
      f32x4 acc[4][2] = {};
#pragma unroll
      for (int kk = 0; kk < 256; kk += 64) {
#pragma unroll
        for (int kb = 0; kb < 2; ++kb) {
          const int ks = (kk >> 3) + kb * 4 + lq;
          bf16x8 af[4], bfr[2];
#pragma unroll
          for (int mi = 0; mi < 4; ++mi) {
            int r = mi * 16 + lr;
            af[mi] = *(const bf16x8*)&ts[(r * 32 + (ks ^ (r & 31))) * 8];
          }
#pragma unroll
          for (int ni = 0; ni < 2; ++ni) {
            int n = wv * 32 + ni * 16 + lr;
            bfr[ni] = *(const bf16x8*)&w1e[(size_t)n * 256 + kk + kb * 32 + lq * 8];
          }
#pragma unroll
          for (int mi = 0; mi < 4; ++mi)
#pragma unroll
            for (int ni = 0; ni < 2; ++ni)
              acc[mi][ni] = __builtin_amdgcn_mfma_f32_16x16x32_bf16(af[mi], bfr[ni], acc[mi][ni], 0, 0, 0);
        }
      }
      float b1v[2];
#pragma unroll
      for (int ni = 0; ni < 2; ++ni) b1v[ni] = b1[ex * 256 + wv * 32 + ni * 16 + lr];
      __syncthreads();   // all x-tile reads done before h overlay
#pragma unroll
      for (int mi = 0; mi < 4; ++mi)
#pragma unroll
        for (int ni = 0; ni < 2; ++ni)
#pragma unroll
          for (int rr = 0; rr < 4; ++rr) {
            int m = mi * 16 + lq * 4 + rr;
            int n = wv * 32 + ni * 16 + lr;
            float v = acc[mi][ni][rr] + b1v[ni];
            v = v > 0.f ? v : 0.f;
            ts[(m * 32 + ((n >> 3) ^ (m & 31))) * 8 + (n & 7)] = (bf16_t)v;
          }
    }
    __syncthreads();
    // Phase 2: out = (h @ W2 + b2) * gate
    const bf16_t* w2e = w2t + (size_t)ex * 65536;
    {
      f32x4 acc[4][2] = {};
#pragma unroll
      for (int kk = 0; kk < 256; kk += 64) {
#pragma unroll
        for (int kb = 0; kb < 2; ++kb) {
          const int ks = (kk >> 3) + kb * 4 + lq;
          bf16x8 af[4], bfr[2];
#pragma unroll
          for (int mi = 0; mi < 4; ++mi) {
            int r = mi * 16 + lr;
            af[mi] = *(const bf16x8*)&ts[(r * 32 + (ks ^ (r & 31))) * 8];
          }
#pragma unroll
          for (int ni = 0; ni < 2; ++ni) {
            int n = wv * 32 + ni * 16 + lr;
            bfr[ni] = *(const bf16x8*)&w2e[(size_t)n * 256 + kk + kb * 32 + lq * 8];
          }
#pragma unroll
          for (int mi = 0; mi < 4; ++mi)
#pragma unroll
            for (int ni = 0; ni < 2; ++ni)
              acc[mi][ni] = __builtin_amdgcn_mfma_f32_16x16x32_bf16(af[mi], bfr[ni], acc[mi][ni], 0, 0, 0);
        }
      }
      float b2v[2];
#pragma unroll
      for (int ni = 0; ni < 2; ++ni) b2v[ni] = b2[ex * 256 + wv * 32 + ni * 16 + lr];
#pragma unroll
      for (int mi = 0; mi < 4; ++mi)
#pragma unroll
        for (int rr = 0; rr < 4; ++rr) {
          int m = mi * 16 + lq * 4 + rr;
          int row = tm * 64 + m;
          if (row < ccnt) {
            int tk = sidx[m];
            float g = sgv[m];
#pragma unroll
            for (int ni = 0; ni < 2; ++ni) {
              int n = wv * 32 + ni * 16 + lr;
              out[(size_t)tk * 256 + n] = (acc[mi][ni][rr] + b2v[ni]) * g;
            }
          }
        }
    }
    __syncthreads();   // protect ts/sidx before next tile
  }
}

extern "C" void kernel_launch(void* const* d_in, const int* in_sizes, int n_in,
                              void* d_out, int out_size, void* d_ws, size_t ws_size,
                              hipStream_t stream) {
  (void)in_sizes; (void)n_in; (void)out_size; (void)ws_size;
  const float* x  = (const float*)d_in[0];
  const float* wg = (const float*)d_in[1];
  const float* W1 = (const float*)d_in[2];
  const float* b1 = (const float*)d_in[3];
  const float* W2 = (const float*)d_in[4];
  const float* b2 = (const float*)d_in[5];
  float* out = (float*)d_out;

  char* ws = (char*)d_ws;
  size_t off = 0;
  auto alloc = [&](size_t bytes) {
    void* p = ws + off;
    off += (bytes + 255) & ~(size_t)255;
    return p;
  };
  bf16_t* xb     = (bf16_t*)alloc((size_t)NTOK * 256 * 2);      // 32 MB
  bf16_t* w1t    = (bf16_t*)alloc((size_t)NEXP * 256 * 256 * 2);
  bf16_t* w2t    = (bf16_t*)alloc((size_t)NEXP * 256 * 256 * 2);
  int*    idxbuf = (int*)alloc((size_t)NTOK * 4);               // dense, 256 KB
  float*  gvb    = (float*)alloc((size_t)NTOK * 4);
  int*    gcnt   = (int*)alloc((size_t)NBLK * NEXP * 4);        // 8 KB

  void* args[] = {
    (void*)&x, (void*)&wg, (void*)&W1, (void*)&b1, (void*)&W2, (void*)&b2,
    (void*)&out, (void*)&xb, (void*)&w1t, (void*)&w2t,
    (void*)&idxbuf, (void*)&gvb, (void*)&gcnt
  };
  hipLaunchCooperativeKernel((const void*)mega_kernel, dim3(NBLK), dim3(TPB),
                             args, 0, stream);
}

// Round 7
// 173.264 us; speedup vs baseline: 2.3644x; 2.3644x over previous
//
#include <hip/hip_runtime.h>
#include <hip/hip_bf16.h>
#include <math.h>

#define NTOK 65536
#define DMODEL 256
#define NEXP 8
#define CAP 65536
#define MAXTILES 1040
#define CSTRIDE 64   // counter spacing in ints (256 B) - one L2 line per expert

typedef __bf16 bf16_t;
typedef __bf16 bf16x8 __attribute__((ext_vector_type(8)));
typedef float f32x4 __attribute__((ext_vector_type(4)));

// async global->LDS, 16B per lane. Global addr may be per-lane (gather);
// LDS dest = wave-uniform base + lane*16.
__device__ inline void async16(const void* g, void* l) {
  __builtin_amdgcn_global_load_lds(
      (const __attribute__((address_space(1))) unsigned int*)g,
      (__attribute__((address_space(3))) unsigned int*)l, 16, 0, 0);
}

// Gate v8 + fused weight pack. Changes vs validated v7 (43us, occ 16%):
//  - x tile staged in TWO 128-dim halves (xs 32KB instead of 64KB): LDS
//    46.6KB -> 3 blocks/CU (was 2). Same source-swizzle scheme per half.
//  - wave wv covers dims {wv*32..+32} in each half (4 chains of 8 per half);
//    same fmaf chain structure, chain partition across waves differs from v7
//    (tolerated: mega-round validated this class; double accumulation).
//  - weights read directly from wg[e][d] with wave-uniform addresses
//    (s_load) -> prep/wgT kernel eliminated.
//  - weight PACK fused here: 2 MFMA-fragment jobs per block convert
//    W1/W2 fp32 -> bf16 in fragment-major layout (each fragment = 1KB
//    contiguous = one coalesced wave load in moe). Same (bf16)(fp32)
//    rounding as the old castT -> moe math bit-identical. Pack global
//    loads/stores are issued under the half-0 staging latency.
//  - reduce/softmax/ballot/atomic/scatter tail: v7 VERBATIM.
__global__ __launch_bounds__(256) void gate_pack_kernel(
    const float* __restrict__ x, const float* __restrict__ wg,
    const float* __restrict__ W1, const float* __restrict__ W2,
    bf16_t* __restrict__ xb, float* __restrict__ gateval,
    int* __restrict__ counts, int* __restrict__ idxbuf,
    bf16_t* __restrict__ w1p, bf16_t* __restrict__ w2p) {
  __shared__ __align__(16) float xs[64 * 128];   // 32 KB, one 128-dim half
  __shared__ double part[3][64][9];              // 13.5 KB
  const int th = threadIdx.x;
  const int lane = th & 63;
  const int wv = th >> 6;                        // 0..3
  const int tokbase = blockIdx.x * 64;
  const int xm = lane & 31;
  double acc[8] = {0, 0, 0, 0, 0, 0, 0, 0};

  // ---- issue stage of half 0 (2048 16B slots; phys slot p holds logical
  // f32-slot (p&31)^(r&31) of row r=p>>5) ----
#pragma unroll
  for (int i = 0; i < 8; ++i) {
    int p = i * 256 + th;
    int r = p >> 5, c = (p & 31) ^ (r & 31);
    async16(x + (size_t)(tokbase + r) * 256 + c * 4, &xs[(i * 256 + wv * 64) * 4]);
  }
  // ---- pack 2 weight fragments (global-only; overlaps staging latency).
  // Fragment f: mat=f>>10 (W1/W2), e=(f>>7)&7, kf=(f>>4)&7, nt=f&15.
  // Packed element (lane,j): k=kf*32+(lane>>4)*8+j, n=nt*16+(lane&15).
#pragma unroll
  for (int jj = 0; jj < 2; ++jj) {
    int f = blockIdx.x * 2 + jj;
    int mat = f >> 10, e = (f >> 7) & 7, kf = (f >> 4) & 7, nt = f & 15;
    const float* src = (mat == 0 ? W1 : W2) + (size_t)e * 65536;
    bf16_t* dst = (mat == 0 ? w1p : w2p) + (((size_t)e * 8 + kf) * 16 + nt) * 512;
#pragma unroll
    for (int rep = 0; rep < 2; ++rep) {
      int kl = rep * 16 + (th >> 4), nl = th & 15;
      float v = src[(size_t)(kf * 32 + kl) * 256 + nt * 16 + nl];
      int lanep = nl + 16 * (kl >> 3), j = kl & 7;
      dst[lanep * 8 + j] = (bf16_t)v;
    }
  }
  __syncthreads();   // half 0 landed (drains vmcnt)

#pragma unroll
  for (int h = 0; h < 2; ++h) {
    // cast pass: 1024 bf16 16B-slots -> contiguous xb stores
#pragma unroll
    for (int i = 0; i < 4; ++i) {
      int p = i * 256 + th;
      int r = p >> 4, cb = p & 15, mk = r & 31;
      f32x4 a = *(const f32x4*)&xs[r * 128 + (((2 * cb) ^ mk) * 4)];
      f32x4 b = *(const f32x4*)&xs[r * 128 + (((2 * cb + 1) ^ mk) * 4)];
      bf16x8 bv;
      bv[0] = (bf16_t)a[0]; bv[1] = (bf16_t)a[1];
      bv[2] = (bf16_t)a[2]; bv[3] = (bf16_t)a[3];
      bv[4] = (bf16_t)b[0]; bv[5] = (bf16_t)b[1];
      bv[6] = (bf16_t)b[2]; bv[7] = (bf16_t)b[3];
      *(bf16x8*)(xb + (size_t)(tokbase + r) * 256 + h * 128 + cb * 8) = bv;
    }
    // dot: wave wv covers dims h*128 + wv*32 .. +32 (4 chains of 8)
#pragma unroll
    for (int g = 0; g < 4; ++g) {
      int c0 = wv * 8 + 2 * g;
      f32x4 a = *(const f32x4*)&xs[lane * 128 + ((c0 ^ xm) * 4)];
      f32x4 b = *(const f32x4*)&xs[lane * 128 + (((c0 + 1) ^ xm) * 4)];
      float xv[8] = {a[0], a[1], a[2], a[3], b[0], b[1], b[2], b[3]};
#pragma unroll
      for (int e = 0; e < 8; ++e) {
        const float* wge = wg + e * 256 + h * 128 + wv * 32 + g * 8;  // wave-uniform
        float s = 0.f;
#pragma unroll
        for (int j2 = 0; j2 < 8; ++j2) s = fmaf(xv[j2], wge[j2], s);
        acc[e] += (double)s;
      }
    }
    if (h == 0) {
      __syncthreads();   // all half-0 reads done before restage
#pragma unroll
      for (int i = 0; i < 8; ++i) {
        int p = i * 256 + th;
        int r = p >> 5, c = (p & 31) ^ (r & 31);
        async16(x + (size_t)(tokbase + r) * 256 + 128 + c * 4, &xs[(i * 256 + wv * 64) * 4]);
      }
      __syncthreads(); // half 1 landed
    }
  }

  if (wv > 0) {
#pragma unroll
    for (int e = 0; e < 8; ++e) part[wv - 1][lane][e] = acc[e];
  }
  __syncthreads();
  if (wv == 0) {
#pragma unroll
    for (int s2 = 0; s2 < 3; ++s2)
#pragma unroll
      for (int e = 0; e < 8; ++e) acc[e] += part[s2][lane][e];
    double m = acc[0]; int bi = 0;
#pragma unroll
    for (int e = 1; e < 8; ++e) if (acc[e] > m) { m = acc[e]; bi = e; }
    float denom = 0.f;
#pragma unroll
    for (int e = 0; e < 8; ++e) denom += __expf((float)(acc[e] - m));
    const int tok = tokbase + lane;
    gateval[tok] = 1.0f / denom;
    unsigned long long mymask = 0;
#pragma unroll
    for (int e = 0; e < NEXP; ++e) {
      unsigned long long mk = __ballot(bi == e);
      if (lane == e) mymask = mk;
    }
    int mybase = 0;
    if (lane < NEXP) mybase = atomicAdd(&counts[lane * CSTRIDE], (int)__popcll(mymask));
#pragma unroll
    for (int e = 0; e < NEXP; ++e) {
      unsigned long long mk = __ballot(bi == e);
      int b = __shfl(mybase, e, 64);
      if (bi == e) {
        int pos = b + (int)__popcll(mk & ((1ull << lane) - 1ull));
        idxbuf[e * CAP + pos] = tok;
      }
    }
  }
}

// Fused MoE GEMM v5 = round-5 body with two changes:
//  1. B fragments load from the PACKED layout: address = wave-uniform base +
//     lane*16B -> one contiguous 1KB coalesced load per fragment (the old
//     w1t[n*256+k] form fragmented into ~32 L2 requests at 512B lane stride;
//     six rounds showed ~70us invariant to occupancy/regs/conflicts -> the
//     exposed fragmented-load latency chain is the remaining suspect).
//  2. Tile map derived from counts directly (scan kernel folded in).
// A-staging, h LDS overlay, epilogues, MFMA order: unchanged (bit-identical).
__global__ __launch_bounds__(512, 4) void moe_gemm_kernel(
    const bf16_t* __restrict__ xb, const bf16_t* __restrict__ w1p,
    const bf16_t* __restrict__ w2p, const float* __restrict__ b1,
    const float* __restrict__ b2, const float* __restrict__ gateval,
    const int* __restrict__ counts, const int* __restrict__ idxbuf,
    float* __restrict__ out) {
  // tile map: block b -> (expert ex, tile tm)
  int ex = -1, tm = 0, a2 = 0, cnte = 0;
#pragma unroll
  for (int e2 = 0; e2 < 8; ++e2) {
    int c = counts[e2 * CSTRIDE];
    int n = (c + 63) >> 6;
    if ((int)blockIdx.x >= a2 && (int)blockIdx.x < a2 + n) {
      ex = e2; tm = (int)blockIdx.x - a2; cnte = c;
    }
    a2 += n;
  }
  if (ex < 0) return;
  const int ccnt = cnte;
  __shared__ __align__(16) bf16_t ts[64 * 256];   // 32 KB: x tile, then h tile
  __shared__ int sidx[64];
  __shared__ float sgv[64];
  const int th = threadIdx.x;
  const int lane = th & 63, wv = th >> 6;         // wv 0..7
  const int lr = lane & 15, lq = lane >> 4;
  if (th < 64) {
    int r = tm * 64 + th;
    int t = idxbuf[ex * CAP + (r < ccnt ? r : ccnt - 1)];
    sidx[th] = t;
    sgv[th] = gateval[t];
  }
  __syncthreads();
  // Stage x tile: 2048 16B slots over 512 threads; phys slot p holds
  // logical k-slot (p&31)^(r&31) of row r = p>>5.
#pragma unroll
  for (int i = 0; i < 4; ++i) {
    int p = i * 512 + th;
    int r = p >> 5, s = (p & 31) ^ (r & 31);
    async16(xb + (size_t)sidx[r] * 256 + s * 8, &ts[(i * 512 + wv * 64) * 8]);
  }
  __syncthreads();

  // ---- Phase 1: h = relu(x @ W1 + b1), wave wv owns cols wv*32..+32 ----
  const bf16_t* w1e = w1p + (size_t)ex * 65536;
  {
    f32x4 acc[4][2] = {};
#pragma unroll
    for (int kk = 0; kk < 256; kk += 64) {
#pragma unroll
      for (int kb = 0; kb < 2; ++kb) {
        const int ks = (kk >> 3) + kb * 4 + lq;
        const int kf = (kk >> 5) + kb;            // 0..7
        bf16x8 af[4], bfr[2];
#pragma unroll
        for (int mi = 0; mi < 4; ++mi) {
          int r = mi * 16 + lr;
          af[mi] = *(const bf16x8*)&ts[(r * 32 + (ks ^ (r & 31))) * 8];
        }
#pragma unroll
        for (int ni = 0; ni < 2; ++ni)            // coalesced: base + lane*16B
          bfr[ni] = *(const bf16x8*)&w1e[((size_t)kf * 16 + wv * 2 + ni) * 512 + lane * 8];
#pragma unroll
        for (int mi = 0; mi < 4; ++mi)
#pragma unroll
          for (int ni = 0; ni < 2; ++ni)
            acc[mi][ni] = __builtin_amdgcn_mfma_f32_16x16x32_bf16(af[mi], bfr[ni], acc[mi][ni], 0, 0, 0);
      }
    }
    float b1v[2];
#pragma unroll
    for (int ni = 0; ni < 2; ++ni) b1v[ni] = b1[ex * 256 + wv * 32 + ni * 16 + lr];
    __syncthreads();   // all x-tile reads done before h overlay
#pragma unroll
    for (int mi = 0; mi < 4; ++mi)
#pragma unroll
      for (int ni = 0; ni < 2; ++ni)
#pragma unroll
        for (int rr = 0; rr < 4; ++rr) {
          int m = mi * 16 + lq * 4 + rr;          // C layout: row=quad*4+reg
          int n = wv * 32 + ni * 16 + lr;         //           col=lane&15
          float v = acc[mi][ni][rr] + b1v[ni];
          v = v > 0.f ? v : 0.f;
          ts[(m * 32 + ((n >> 3) ^ (m & 31))) * 8 + (n & 7)] = (bf16_t)v;
        }
  }
  __syncthreads();

  // ---- Phase 2: out = (h @ W2 + b2) * gate ----
  const bf16_t* w2e = w2p + (size_t)ex * 65536;
  {
    f32x4 acc[4][2] = {};
#pragma unroll
    for (int kk = 0; kk < 256; kk += 64) {
#pragma unroll
      for (int kb = 0; kb < 2; ++kb) {
        const int ks = (kk >> 3) + kb * 4 + lq;
        const int kf = (kk >> 5) + kb;
        bf16x8 af[4], bfr[2];
#pragma unroll
        for (int mi = 0; mi < 4; ++mi) {
          int r = mi * 16 + lr;
          af[mi] = *(const bf16x8*)&ts[(r * 32 + (ks ^ (r & 31))) * 8];
        }
#pragma unroll
        for (int ni = 0; ni < 2; ++ni)
          bfr[ni] = *(const bf16x8*)&w2e[((size_t)kf * 16 + wv * 2 + ni) * 512 + lane * 8];
#pragma unroll
        for (int mi = 0; mi < 4; ++mi)
#pragma unroll
          for (int ni = 0; ni < 2; ++ni)
            acc[mi][ni] = __builtin_amdgcn_mfma_f32_16x16x32_bf16(af[mi], bfr[ni], acc[mi][ni], 0, 0, 0);
      }
    }
    float b2v[2];
#pragma unroll
    for (int ni = 0; ni < 2; ++ni) b2v[ni] = b2[ex * 256 + wv * 32 + ni * 16 + lr];
#pragma unroll
    for (int mi = 0; mi < 4; ++mi)
#pragma unroll
      for (int rr = 0; rr < 4; ++rr) {
        int m = mi * 16 + lq * 4 + rr;
        int row = tm * 64 + m;
        if (row < ccnt) {
          int tk = sidx[m];
          float g = sgv[m];
#pragma unroll
          for (int ni = 0; ni < 2; ++ni) {
            int n = wv * 32 + ni * 16 + lr;
            out[(size_t)tk * 256 + n] = (acc[mi][ni][rr] + b2v[ni]) * g;
          }
        }
      }
  }
}

extern "C" void kernel_launch(void* const* d_in, const int* in_sizes, int n_in,
                              void* d_out, int out_size, void* d_ws, size_t ws_size,
                              hipStream_t stream) {
  (void)in_sizes; (void)n_in; (void)out_size; (void)ws_size;
  const float* x  = (const float*)d_in[0];
  const float* wg = (const float*)d_in[1];
  const float* W1 = (const float*)d_in[2];
  const float* b1 = (const float*)d_in[3];
  const float* W2 = (const float*)d_in[4];
  const float* b2 = (const float*)d_in[5];
  float* out = (float*)d_out;

  char* ws = (char*)d_ws;
  size_t off = 0;
  auto alloc = [&](size_t bytes) {
    void* p = ws + off;
    off += (bytes + 255) & ~(size_t)255;
    return p;
  };
  bf16_t* xb     = (bf16_t*)alloc((size_t)NTOK * DMODEL * 2);   // 32 MB
  bf16_t* w1p    = (bf16_t*)alloc((size_t)NEXP * 256 * 256 * 2);
  bf16_t* w2p    = (bf16_t*)alloc((size_t)NEXP * 256 * 256 * 2);
  int*    idxbuf = (int*)alloc((size_t)NEXP * CAP * 4);         // 2 MB
  float*  gv     = (float*)alloc((size_t)NTOK * 4);
  int*    counts = (int*)alloc((size_t)NEXP * CSTRIDE * 4);     // 256B-spread

  hipMemsetAsync(counts, 0, (size_t)NEXP * CSTRIDE * 4, stream);
  hipLaunchKernelGGL(gate_pack_kernel, dim3(NTOK / 64), dim3(256), 0, stream,
                     x, wg, W1, W2, xb, gv, counts, idxbuf, w1p, w2p);
  hipLaunchKernelGGL(moe_gemm_kernel, dim3(MAXTILES), dim3(512), 0, stream,
                     xb, w1p, w2p, b1, b2, gv, counts, idxbuf, out);
}